// Round 1
// baseline (16561.098 us; speedup 1.0000x reference)
//
#include <hip/hip_runtime.h>

#define TPB 256

// ---------------- degree ----------------
__global__ void count_deg(const int* __restrict__ dst, int* __restrict__ cnt, int nE) {
    int e = blockIdx.x * blockDim.x + threadIdx.x;
    if (e < nE) atomicAdd(&cnt[dst[e]], 1);
}

// in-place: read int count, write float rsqrt(count+1) to the same buffer
__global__ void make_dis(int* __restrict__ cnt_dis, int n) {
    int i = blockIdx.x * blockDim.x + threadIdx.x;
    if (i < n) {
        int c = cnt_dis[i];
        float v = rsqrtf((float)c + 1.0f);
        ((float*)cnt_dis)[i] = v;
    }
}

// ---------------- layer 1 node kernel: h = x*W1 (in_dim=1) ----------------
// writes hs = h*dis, acc = h*dis^2
__global__ void node_l1(const float* __restrict__ x, const float* __restrict__ W1,
                        const float* __restrict__ dis,
                        float* __restrict__ hs, float* __restrict__ acc, int n) {
    int i = blockIdx.x * blockDim.x + threadIdx.x;
    if (i >= n) return;
    float xv = x[i];
    float d  = dis[i];
    float d2 = d * d;
    float4 w0 = ((const float4*)W1)[0];
    float4 w1 = ((const float4*)W1)[1];
    float4 h0 = make_float4(xv*w0.x, xv*w0.y, xv*w0.z, xv*w0.w);
    float4 h1 = make_float4(xv*w1.x, xv*w1.y, xv*w1.z, xv*w1.w);
    float4* hsp  = (float4*)(hs  + (size_t)i * 8);
    float4* accp = (float4*)(acc + (size_t)i * 8);
    hsp[0]  = make_float4(h0.x*d,  h0.y*d,  h0.z*d,  h0.w*d);
    hsp[1]  = make_float4(h1.x*d,  h1.y*d,  h1.z*d,  h1.w*d);
    accp[0] = make_float4(h0.x*d2, h0.y*d2, h0.z*d2, h0.w*d2);
    accp[1] = make_float4(h1.x*d2, h1.y*d2, h1.z*d2, h1.w*d2);
}

// ---------------- general node kernel (layers 2..4) ----------------
// g_raw = previous layer's accumulated output (pre-bias). Apply +b_prev, relu,
// then h = g @ W ; hs = h*dis ; acc = h*dis^2
__global__ void node_gen(const float* __restrict__ g_raw, const float* __restrict__ b_prev,
                         const float* __restrict__ W, const float* __restrict__ dis,
                         float* __restrict__ hs, float* __restrict__ acc, int n) {
    int i = blockIdx.x * blockDim.x + threadIdx.x;
    if (i >= n) return;
    const float4* gp = (const float4*)(g_raw + (size_t)i * 8);
    float4 g0 = gp[0], g1 = gp[1];
    float in[8];
    in[0] = g0.x; in[1] = g0.y; in[2] = g0.z; in[3] = g0.w;
    in[4] = g1.x; in[5] = g1.y; in[6] = g1.z; in[7] = g1.w;
#pragma unroll
    for (int k = 0; k < 8; ++k) {
        float v = in[k] + b_prev[k];
        in[k] = v > 0.0f ? v : 0.0f;
    }
    float h[8];
#pragma unroll
    for (int j = 0; j < 8; ++j) {
        float s = 0.0f;
#pragma unroll
        for (int k = 0; k < 8; ++k) s += in[k] * W[k * 8 + j];
        h[j] = s;
    }
    float d = dis[i], d2 = d * d;
    float4* hsp  = (float4*)(hs  + (size_t)i * 8);
    float4* accp = (float4*)(acc + (size_t)i * 8);
    hsp[0]  = make_float4(h[0]*d,  h[1]*d,  h[2]*d,  h[3]*d);
    hsp[1]  = make_float4(h[4]*d,  h[5]*d,  h[6]*d,  h[7]*d);
    accp[0] = make_float4(h[0]*d2, h[1]*d2, h[2]*d2, h[3]*d2);
    accp[1] = make_float4(h[4]*d2, h[5]*d2, h[6]*d2, h[7]*d2);
}

// ---------------- edge push: acc[dst] += hs[src] * dis[dst] ----------------
__global__ void edge_push(const int* __restrict__ src, const int* __restrict__ dst,
                          const float* __restrict__ dis, const float* __restrict__ hs,
                          float* __restrict__ acc, int nE) {
    int e = blockIdx.x * blockDim.x + threadIdx.x;
    if (e >= nE) return;
    int s = src[e];
    int t = dst[e];
    float d = dis[t];
    const float4* hp = (const float4*)(hs + (size_t)s * 8);
    float4 a = hp[0], b = hp[1];
    float* p = acc + (size_t)t * 8;
    unsafeAtomicAdd(p + 0, a.x * d);
    unsafeAtomicAdd(p + 1, a.y * d);
    unsafeAtomicAdd(p + 2, a.z * d);
    unsafeAtomicAdd(p + 3, a.w * d);
    unsafeAtomicAdd(p + 4, b.x * d);
    unsafeAtomicAdd(p + 5, b.y * d);
    unsafeAtomicAdd(p + 6, b.z * d);
    unsafeAtomicAdd(p + 7, b.w * d);
}

// ---------------- final gather: out[i][:] = acc[idx[i]][:] + b4 ----------------
__global__ void gather_out(const float* __restrict__ acc, const int* __restrict__ idx,
                           const float* __restrict__ b, float* __restrict__ out, int B) {
    int t = blockIdx.x * blockDim.x + threadIdx.x;
    if (t >= B * 8) return;
    int i = t >> 3, j = t & 7;
    out[t] = acc[(size_t)idx[i] * 8 + j] + b[j];
}

extern "C" void kernel_launch(void* const* d_in, const int* in_sizes, int n_in,
                              void* d_out, int out_size, void* d_ws, size_t ws_size,
                              hipStream_t stream) {
    const float* x   = (const float*)d_in[0];
    const int*   ei  = (const int*)d_in[1];
    const int*   idx = (const int*)d_in[2];
    const float* W1  = (const float*)d_in[3];
    const float* b1  = (const float*)d_in[4];
    const float* W2  = (const float*)d_in[5];
    const float* b2  = (const float*)d_in[6];
    const float* W3  = (const float*)d_in[7];
    const float* b3  = (const float*)d_in[8];
    const float* W4  = (const float*)d_in[9];
    const float* b4  = (const float*)d_in[10];

    const int n = in_sizes[0];      // 1,000,000 nodes
    const int E = in_sizes[1] / 2;  // 10,000,000 edges
    const int B = in_sizes[2];      // 64 graphs

    const int* src = ei;
    const int* dst = ei + E;

    // workspace layout: dis (n floats) | A (n*8) | Bb (n*8) | Cc (n*8)  ~= 100 MB
    float* dis = (float*)d_ws;
    float* A   = dis + n;
    float* Bb  = A + (size_t)n * 8;
    float* Cc  = Bb + (size_t)n * 8;

    const int gn = (n + TPB - 1) / TPB;
    const int ge = (E + TPB - 1) / TPB;

    hipMemsetAsync(dis, 0, (size_t)n * sizeof(int), stream);
    count_deg<<<ge, TPB, 0, stream>>>(dst, (int*)dis, E);
    make_dis<<<gn, TPB, 0, stream>>>((int*)dis, n);

    // layer 1: x -> A(hs), Bb(acc)
    node_l1<<<gn, TPB, 0, stream>>>(x, W1, dis, A, Bb, n);
    edge_push<<<ge, TPB, 0, stream>>>(src, dst, dis, A, Bb, E);

    // layer 2: Bb -> A(hs), Cc(acc)
    node_gen<<<gn, TPB, 0, stream>>>(Bb, b1, W2, dis, A, Cc, n);
    edge_push<<<ge, TPB, 0, stream>>>(src, dst, dis, A, Cc, E);

    // layer 3: Cc -> A(hs), Bb(acc)
    node_gen<<<gn, TPB, 0, stream>>>(Cc, b2, W3, dis, A, Bb, n);
    edge_push<<<ge, TPB, 0, stream>>>(src, dst, dis, A, Bb, E);

    // layer 4: Bb -> A(hs), Cc(acc)
    node_gen<<<gn, TPB, 0, stream>>>(Bb, b3, W4, dis, A, Cc, n);
    edge_push<<<ge, TPB, 0, stream>>>(src, dst, dis, A, Cc, E);

    gather_out<<<(B * 8 + TPB - 1) / TPB, TPB, 0, stream>>>(Cc, idx, b4, (float*)d_out, B);
}

// Round 2
// 2139.811 us; speedup vs baseline: 7.7395x; 7.7395x over previous
//
#include <hip/hip_runtime.h>

#define TPB 256

// ---------------- degree count: cnt[dst]++ ----------------
__global__ void count_deg(const int* __restrict__ dst, int* __restrict__ cnt, int nE) {
    int e = blockIdx.x * blockDim.x + threadIdx.x;
    if (e < nE) atomicAdd(&cnt[dst[e]], 1);
}

// dis = rsqrt(cnt + 1)
__global__ void make_dis(const int* __restrict__ cnt, float* __restrict__ dis, int n) {
    int i = blockIdx.x * blockDim.x + threadIdx.x;
    if (i < n) dis[i] = rsqrtf((float)cnt[i] + 1.0f);
}

// ---------------- exclusive scan of cnt -> rowptr (3 kernels) ----------------
__global__ void scan_blocks(const int* __restrict__ cnt, int* __restrict__ rowptr,
                            int* __restrict__ bsum, int n) {
    __shared__ int lds[TPB];
    int i = blockIdx.x * TPB + threadIdx.x;
    int v = (i < n) ? cnt[i] : 0;
    lds[threadIdx.x] = v;
    __syncthreads();
#pragma unroll
    for (int off = 1; off < TPB; off <<= 1) {
        int t = (threadIdx.x >= off) ? lds[threadIdx.x - off] : 0;
        __syncthreads();
        lds[threadIdx.x] += t;
        __syncthreads();
    }
    if (i < n) rowptr[i] = lds[threadIdx.x] - v;           // exclusive, block-local
    if (threadIdx.x == TPB - 1) bsum[blockIdx.x] = lds[TPB - 1];
}

__global__ void scan_bsum(int* __restrict__ bsum, int nb) {
    __shared__ int lds[TPB];
    int carry = 0;
    for (int base = 0; base < nb; base += TPB) {
        int i = base + threadIdx.x;
        int v = (i < nb) ? bsum[i] : 0;
        lds[threadIdx.x] = v;
        __syncthreads();
        for (int off = 1; off < TPB; off <<= 1) {
            int t = (threadIdx.x >= off) ? lds[threadIdx.x - off] : 0;
            __syncthreads();
            lds[threadIdx.x] += t;
            __syncthreads();
        }
        int incl = lds[threadIdx.x];
        if (i < nb) bsum[i] = carry + incl - v;            // exclusive across chunks
        carry += lds[TPB - 1];
        __syncthreads();
    }
}

__global__ void add_off(int* __restrict__ rowptr, const int* __restrict__ bsum,
                        int n, int nE) {
    int i = blockIdx.x * TPB + threadIdx.x;
    if (i < n) rowptr[i] += bsum[blockIdx.x];
    if (i == 0) rowptr[n] = nE;
}

// ---------------- CSR fill: col[rowptr[dst] + pos] = src ----------------
__global__ void fill_csr(const int* __restrict__ src, const int* __restrict__ dst,
                         const int* __restrict__ rowptr, int* __restrict__ fillcnt,
                         int* __restrict__ col, int nE) {
    int e = blockIdx.x * blockDim.x + threadIdx.x;
    if (e >= nE) return;
    int t = dst[e];
    int p = atomicAdd(&fillcnt[t], 1);
    col[rowptr[t] + p] = src[e];
}

// ---------------- layer 1 node kernel: hs = (x*W1)*dis ----------------
__global__ void node_l1(const float* __restrict__ x, const float* __restrict__ W1,
                        const float* __restrict__ dis, float* __restrict__ hs, int n) {
    int i = blockIdx.x * blockDim.x + threadIdx.x;
    if (i >= n) return;
    float xd = x[i] * dis[i];
    float4 w0 = ((const float4*)W1)[0];
    float4 w1 = ((const float4*)W1)[1];
    float4* hsp = (float4*)(hs + (size_t)i * 8);
    hsp[0] = make_float4(xd * w0.x, xd * w0.y, xd * w0.z, xd * w0.w);
    hsp[1] = make_float4(xd * w1.x, xd * w1.y, xd * w1.z, xd * w1.w);
}

// ---------------- general node kernel: hs = relu(g + b_prev) @ W * dis ----------------
__global__ void node_gen(const float* __restrict__ g_raw, const float* __restrict__ b_prev,
                         const float* __restrict__ W, const float* __restrict__ dis,
                         float* __restrict__ hs, int n) {
    int i = blockIdx.x * blockDim.x + threadIdx.x;
    if (i >= n) return;
    const float4* gp = (const float4*)(g_raw + (size_t)i * 8);
    float4 g0 = gp[0], g1 = gp[1];
    float in[8] = {g0.x, g0.y, g0.z, g0.w, g1.x, g1.y, g1.z, g1.w};
#pragma unroll
    for (int k = 0; k < 8; ++k) {
        float v = in[k] + b_prev[k];
        in[k] = v > 0.0f ? v : 0.0f;
    }
    float h[8];
#pragma unroll
    for (int j = 0; j < 8; ++j) {
        float s = 0.0f;
#pragma unroll
        for (int k = 0; k < 8; ++k) s += in[k] * W[k * 8 + j];
        h[j] = s;
    }
    float d = dis[i];
    float4* hsp = (float4*)(hs + (size_t)i * 8);
    hsp[0] = make_float4(h[0] * d, h[1] * d, h[2] * d, h[3] * d);
    hsp[1] = make_float4(h[4] * d, h[5] * d, h[6] * d, h[7] * d);
}

// ---------------- pull: g[i] = dis[i] * (sum_{c in in(i)} hs[c] + hs[i]) ----------------
__global__ void pull(const int* __restrict__ rowptr, const int* __restrict__ col,
                     const float* __restrict__ dis, const float* __restrict__ hs,
                     float* __restrict__ g, int n) {
    int i = blockIdx.x * blockDim.x + threadIdx.x;
    if (i >= n) return;
    const float4* h4 = (const float4*)hs;
    size_t i2 = (size_t)i * 2;
    float4 a0 = h4[i2], a1 = h4[i2 + 1];          // self-loop term (hs[i])
    int s = rowptr[i], e = rowptr[i + 1];
    for (int k = s; k < e; ++k) {
        size_t c2 = (size_t)col[k] * 2;
        float4 b0 = h4[c2], b1 = h4[c2 + 1];
        a0.x += b0.x; a0.y += b0.y; a0.z += b0.z; a0.w += b0.w;
        a1.x += b1.x; a1.y += b1.y; a1.z += b1.z; a1.w += b1.w;
    }
    float d = dis[i];
    float4* gp = (float4*)(g + (size_t)i * 8);
    gp[0] = make_float4(a0.x * d, a0.y * d, a0.z * d, a0.w * d);
    gp[1] = make_float4(a1.x * d, a1.y * d, a1.z * d, a1.w * d);
}

// ---------------- final gather: out[i][:] = g[idx[i]][:] + b4 ----------------
__global__ void gather_out(const float* __restrict__ g, const int* __restrict__ idx,
                           const float* __restrict__ b, float* __restrict__ out, int B) {
    int t = blockIdx.x * blockDim.x + threadIdx.x;
    if (t >= B * 8) return;
    int i = t >> 3, j = t & 7;
    out[t] = g[(size_t)idx[i] * 8 + j] + b[j];
}

extern "C" void kernel_launch(void* const* d_in, const int* in_sizes, int n_in,
                              void* d_out, int out_size, void* d_ws, size_t ws_size,
                              hipStream_t stream) {
    const float* x   = (const float*)d_in[0];
    const int*   ei  = (const int*)d_in[1];
    const int*   idx = (const int*)d_in[2];
    const float* W1  = (const float*)d_in[3];
    const float* b1  = (const float*)d_in[4];
    const float* W2  = (const float*)d_in[5];
    const float* b2  = (const float*)d_in[6];
    const float* W3  = (const float*)d_in[7];
    const float* b3  = (const float*)d_in[8];
    const float* W4  = (const float*)d_in[9];
    const float* b4  = (const float*)d_in[10];

    const int n = in_sizes[0];      // 1,000,000 nodes
    const int E = in_sizes[1] / 2;  // 10,000,000 edges
    const int B = in_sizes[2];      // 64 graphs

    const int* src = ei;
    const int* dst = ei + E;

    // workspace layout (16B-aligned float4 regions):
    //   rowptr: n+4 ints | col: E ints | dis: n floats | hs: n*8 floats |
    //   g: n*8 floats | bsum: ints
    // aliases (used only during CSR build, before hs/g are written):
    //   cnt = hs region, fillcnt = g region
    int*   rowptr = (int*)d_ws;
    int*   col    = rowptr + (n + 4);
    float* dis    = (float*)(col + E);
    float* hs     = dis + n;
    float* g      = hs + (size_t)n * 8;
    int*   bsum   = (int*)(g + (size_t)n * 8);
    int*   cnt    = (int*)hs;
    int*   fillcnt= (int*)g;

    const int gn = (n + TPB - 1) / TPB;
    const int ge = (E + TPB - 1) / TPB;

    // ---- build CSR (once per call) ----
    hipMemsetAsync(cnt, 0, (size_t)n * sizeof(int), stream);
    count_deg<<<ge, TPB, 0, stream>>>(dst, cnt, E);
    make_dis<<<gn, TPB, 0, stream>>>(cnt, dis, n);
    scan_blocks<<<gn, TPB, 0, stream>>>(cnt, rowptr, bsum, n);
    scan_bsum<<<1, TPB, 0, stream>>>(bsum, gn);
    add_off<<<gn, TPB, 0, stream>>>(rowptr, bsum, n, E);
    hipMemsetAsync(fillcnt, 0, (size_t)n * sizeof(int), stream);
    fill_csr<<<ge, TPB, 0, stream>>>(src, dst, rowptr, fillcnt, col, E);

    // ---- 4 GCN layers, atomic-free pulls ----
    node_l1<<<gn, TPB, 0, stream>>>(x, W1, dis, hs, n);
    pull<<<gn, TPB, 0, stream>>>(rowptr, col, dis, hs, g, n);

    node_gen<<<gn, TPB, 0, stream>>>(g, b1, W2, dis, hs, n);
    pull<<<gn, TPB, 0, stream>>>(rowptr, col, dis, hs, g, n);

    node_gen<<<gn, TPB, 0, stream>>>(g, b2, W3, dis, hs, n);
    pull<<<gn, TPB, 0, stream>>>(rowptr, col, dis, hs, g, n);

    node_gen<<<gn, TPB, 0, stream>>>(g, b3, W4, dis, hs, n);
    pull<<<gn, TPB, 0, stream>>>(rowptr, col, dis, hs, g, n);

    gather_out<<<(B * 8 + TPB - 1) / TPB, TPB, 0, stream>>>(g, idx, b4, (float*)d_out, B);
}

// Round 3
// 1632.130 us; speedup vs baseline: 10.1469x; 1.3111x over previous
//
#include <hip/hip_runtime.h>

#define TPB 256
#define EPT 16            // edges per thread in scatter_buckets
#define BNODES 4096       // nodes per coarse bucket (12 low bits)

// ---------------- coarse histogram of dst >> 12 ----------------
__global__ void hist_buckets(const int* __restrict__ dst, int* __restrict__ hist, int nE) {
    __shared__ int lh[256];
    lh[threadIdx.x] = 0;
    __syncthreads();
    int stride = gridDim.x * blockDim.x;
    for (int e = blockIdx.x * blockDim.x + threadIdx.x; e < nE; e += stride)
        atomicAdd(&lh[dst[e] >> 12], 1);
    __syncthreads();
    if (lh[threadIdx.x]) atomicAdd(&hist[threadIdx.x], lh[threadIdx.x]);
}

// ---------------- exclusive scan of 256 bucket counts ----------------
__global__ void scan256(const int* __restrict__ hist, int* __restrict__ bucketOff,
                        int* __restrict__ tails, int nE) {
    __shared__ int lds[256];
    int t = threadIdx.x;
    int v = hist[t];
    lds[t] = v;
    __syncthreads();
    for (int off = 1; off < 256; off <<= 1) {
        int u = (t >= off) ? lds[t - off] : 0;
        __syncthreads();
        lds[t] += u;
        __syncthreads();
    }
    int excl = lds[t] - v;
    bucketOff[t] = excl;
    tails[t] = excl;
    if (t == 255) bucketOff[256] = lds[255];   // == nE
}

// ---------------- scatter edges into coarse buckets (block-aggregated) ----------------
// payload: (dstLow12 << 20) | src   (requires n <= 2^20)
__global__ void scatter_buckets(const int* __restrict__ src, const int* __restrict__ dst,
                                int* __restrict__ tails, unsigned* __restrict__ bucketData,
                                int nE) {
    __shared__ int hist[256];
    __shared__ int cbase[256];
    int t = threadIdx.x;
    hist[t] = 0;
    __syncthreads();
    long base = (long)blockIdx.x * (TPB * EPT);
    int bk[EPT];
    int lo[EPT];
#pragma unroll
    for (int j = 0; j < EPT; ++j) {
        long e = base + t + (long)j * TPB;
        if (e < nE) {
            int d = dst[e];
            bk[j] = d >> 12;
            lo[j] = d & 4095;
            atomicAdd(&hist[bk[j]], 1);
        } else bk[j] = -1;
    }
    __syncthreads();
    int h = hist[t];
    cbase[t] = (h > 0) ? atomicAdd(&tails[t], h) : 0;
    __syncthreads();
    hist[t] = 0;   // reuse as block-local cursor
    __syncthreads();
#pragma unroll
    for (int j = 0; j < EPT; ++j) {
        long e = base + t + (long)j * TPB;
        if (bk[j] >= 0) {
            int r = atomicAdd(&hist[bk[j]], 1);
            unsigned s = (unsigned)src[e];
            bucketData[cbase[bk[j]] + r] = ((unsigned)lo[j] << 20) | s;
        }
    }
}

// ---------------- per-bucket: degrees -> dis, rowptr (scan), col (contiguous region) ----------------
__global__ void build_csr(const unsigned* __restrict__ bucketData,
                          const int* __restrict__ bucketOff,
                          int* __restrict__ rowptr, int* __restrict__ col,
                          float* __restrict__ dis, int n, int nE) {
    __shared__ int cnt[BNODES];     // 16 KB
    __shared__ int partial[TPB];
    int b = blockIdx.x;
    int t = threadIdx.x;
    for (int j = t; j < BNODES; j += TPB) cnt[j] = 0;
    __syncthreads();
    int e0 = bucketOff[b], e1 = bucketOff[b + 1];
    // count pass
    for (int k = e0 + t; k < e1; k += TPB)
        atomicAdd(&cnt[bucketData[k] >> 20], 1);
    __syncthreads();
    // dis from degree
    int base0 = b << 12;
    for (int j = t; j < BNODES; j += TPB) {
        int node = base0 + j;
        if (node < n) dis[node] = rsqrtf((float)cnt[j] + 1.0f);
    }
    // exclusive scan of cnt[0..4095]: serial-16 per thread + block scan of partials
    int tb = t * 16;
    int loc[16];
    int s = 0;
#pragma unroll
    for (int j = 0; j < 16; ++j) { loc[j] = s; s += cnt[tb + j]; }
    partial[t] = s;
    __syncthreads();
    for (int off = 1; off < TPB; off <<= 1) {
        int u = (t >= off) ? partial[t - off] : 0;
        __syncthreads();
        partial[t] += u;
        __syncthreads();
    }
    int pbase = (t > 0) ? partial[t - 1] : 0;
    __syncthreads();
    // write rowptr; convert cnt to global cursor
#pragma unroll
    for (int j = 0; j < 16; ++j) {
        int node = base0 + tb + j;
        int gbase = e0 + pbase + loc[j];
        cnt[tb + j] = gbase;
        if (node < n) rowptr[node] = gbase;
    }
    if (b == 0 && t == 0) rowptr[n] = nE;
    __syncthreads();
    // scatter pass: col writes land in [e0, e1) — contiguous, L2-resident
    for (int k = e0 + t; k < e1; k += TPB) {
        unsigned p = bucketData[k];
        int pos = atomicAdd(&cnt[p >> 20], 1);
        col[pos] = (int)(p & 0xFFFFFu);
    }
}

// ---------------- layer 1 node kernel: hs = (x*W1)*dis ----------------
__global__ void node_l1(const float* __restrict__ x, const float* __restrict__ W1,
                        const float* __restrict__ dis, float* __restrict__ hs, int n) {
    int i = blockIdx.x * blockDim.x + threadIdx.x;
    if (i >= n) return;
    float xd = x[i] * dis[i];
    float4 w0 = ((const float4*)W1)[0];
    float4 w1 = ((const float4*)W1)[1];
    float4* hsp = (float4*)(hs + (size_t)i * 8);
    hsp[0] = make_float4(xd * w0.x, xd * w0.y, xd * w0.z, xd * w0.w);
    hsp[1] = make_float4(xd * w1.x, xd * w1.y, xd * w1.z, xd * w1.w);
}

// ---------------- general node kernel: hs = relu(g + b_prev) @ W * dis ----------------
__global__ void node_gen(const float* __restrict__ g_raw, const float* __restrict__ b_prev,
                         const float* __restrict__ W, const float* __restrict__ dis,
                         float* __restrict__ hs, int n) {
    int i = blockIdx.x * blockDim.x + threadIdx.x;
    if (i >= n) return;
    const float4* gp = (const float4*)(g_raw + (size_t)i * 8);
    float4 g0 = gp[0], g1 = gp[1];
    float in[8] = {g0.x, g0.y, g0.z, g0.w, g1.x, g1.y, g1.z, g1.w};
#pragma unroll
    for (int k = 0; k < 8; ++k) {
        float v = in[k] + b_prev[k];
        in[k] = v > 0.0f ? v : 0.0f;
    }
    float h[8];
#pragma unroll
    for (int j = 0; j < 8; ++j) {
        float s = 0.0f;
#pragma unroll
        for (int k = 0; k < 8; ++k) s += in[k] * W[k * 8 + j];
        h[j] = s;
    }
    float d = dis[i];
    float4* hsp = (float4*)(hs + (size_t)i * 8);
    hsp[0] = make_float4(h[0] * d, h[1] * d, h[2] * d, h[3] * d);
    hsp[1] = make_float4(h[4] * d, h[5] * d, h[6] * d, h[7] * d);
}

// ---------------- pull: g[i] = dis[i] * (sum_{c in in(i)} hs[c] + hs[i]) ----------------
__global__ void pull(const int* __restrict__ rowptr, const int* __restrict__ col,
                     const float* __restrict__ dis, const float* __restrict__ hs,
                     float* __restrict__ g, int n) {
    int i = blockIdx.x * blockDim.x + threadIdx.x;
    if (i >= n) return;
    const float4* h4 = (const float4*)hs;
    size_t i2 = (size_t)i * 2;
    float4 a0 = h4[i2], a1 = h4[i2 + 1];          // self-loop term (hs[i])
    int s = rowptr[i], e = rowptr[i + 1];
    for (int k = s; k < e; ++k) {
        size_t c2 = (size_t)col[k] * 2;
        float4 b0 = h4[c2], b1 = h4[c2 + 1];
        a0.x += b0.x; a0.y += b0.y; a0.z += b0.z; a0.w += b0.w;
        a1.x += b1.x; a1.y += b1.y; a1.z += b1.z; a1.w += b1.w;
    }
    float d = dis[i];
    float4* gp = (float4*)(g + (size_t)i * 8);
    gp[0] = make_float4(a0.x * d, a0.y * d, a0.z * d, a0.w * d);
    gp[1] = make_float4(a1.x * d, a1.y * d, a1.z * d, a1.w * d);
}

// ---------------- final gather: out[i][:] = g[idx[i]][:] + b4 ----------------
__global__ void gather_out(const float* __restrict__ g, const int* __restrict__ idx,
                           const float* __restrict__ b, float* __restrict__ out, int B) {
    int t = blockIdx.x * blockDim.x + threadIdx.x;
    if (t >= B * 8) return;
    int i = t >> 3, j = t & 7;
    out[t] = g[(size_t)idx[i] * 8 + j] + b[j];
}

extern "C" void kernel_launch(void* const* d_in, const int* in_sizes, int n_in,
                              void* d_out, int out_size, void* d_ws, size_t ws_size,
                              hipStream_t stream) {
    const float* x   = (const float*)d_in[0];
    const int*   ei  = (const int*)d_in[1];
    const int*   idx = (const int*)d_in[2];
    const float* W1  = (const float*)d_in[3];
    const float* b1  = (const float*)d_in[4];
    const float* W2  = (const float*)d_in[5];
    const float* b2  = (const float*)d_in[6];
    const float* W3  = (const float*)d_in[7];
    const float* b3  = (const float*)d_in[8];
    const float* W4  = (const float*)d_in[9];
    const float* b4  = (const float*)d_in[10];

    const int n = in_sizes[0];      // 1,000,000 nodes (requires n <= 2^20 for packing)
    const int E = in_sizes[1] / 2;  // 10,000,000 edges
    const int B = in_sizes[2];      // 64 graphs

    const int* src = ei;
    const int* dst = ei + E;

    // workspace layout (element offsets rounded to 4 for float4 alignment):
    //   rowptr: n+1 | col: E | dis: n | hs: 8n | g: 8n | hist:256 | bucketOff:257 | tails:256
    //   bucketData (E unsigned) aliases hs..g region (consumed before hs is written)
    size_t o_rowptr = 0;
    size_t o_col    = o_rowptr + (((size_t)n + 1 + 3) & ~(size_t)3);
    size_t o_dis    = o_col    + (((size_t)E + 3) & ~(size_t)3);
    size_t o_hs     = o_dis    + (((size_t)n + 3) & ~(size_t)3);
    size_t o_g      = o_hs     + (size_t)n * 8;
    size_t o_small  = o_g      + (size_t)n * 8;

    int*      rowptr     = (int*)d_ws + o_rowptr;
    int*      col        = (int*)d_ws + o_col;
    float*    dis        = (float*)d_ws + o_dis;
    float*    hs         = (float*)d_ws + o_hs;
    float*    g          = (float*)d_ws + o_g;
    int*      hist       = (int*)d_ws + o_small;
    int*      bucketOff  = hist + 256;
    int*      tails      = bucketOff + 260;
    unsigned* bucketData = (unsigned*)hs;   // alias: 40 MB over hs(32MB)+g head

    const int NB = (n + BNODES - 1) / BNODES;   // coarse buckets (<= 256)
    const int gn = (n + TPB - 1) / TPB;
    const int gs = (int)(((long)E + TPB * EPT - 1) / (TPB * EPT));

    // ---- build CSR ----
    hipMemsetAsync(hist, 0, 256 * sizeof(int), stream);
    hist_buckets<<<1024, TPB, 0, stream>>>(dst, hist, E);
    scan256<<<1, 256, 0, stream>>>(hist, bucketOff, tails, E);
    scatter_buckets<<<gs, TPB, 0, stream>>>(src, dst, tails, bucketData, E);
    build_csr<<<NB, TPB, 0, stream>>>(bucketData, bucketOff, rowptr, col, dis, n, E);

    // ---- 4 GCN layers, atomic-free pulls ----
    node_l1<<<gn, TPB, 0, stream>>>(x, W1, dis, hs, n);
    pull<<<gn, TPB, 0, stream>>>(rowptr, col, dis, hs, g, n);

    node_gen<<<gn, TPB, 0, stream>>>(g, b1, W2, dis, hs, n);
    pull<<<gn, TPB, 0, stream>>>(rowptr, col, dis, hs, g, n);

    node_gen<<<gn, TPB, 0, stream>>>(g, b2, W3, dis, hs, n);
    pull<<<gn, TPB, 0, stream>>>(rowptr, col, dis, hs, g, n);

    node_gen<<<gn, TPB, 0, stream>>>(g, b3, W4, dis, hs, n);
    pull<<<gn, TPB, 0, stream>>>(rowptr, col, dis, hs, g, n);

    gather_out<<<(B * 8 + TPB - 1) / TPB, TPB, 0, stream>>>(g, idx, b4, (float*)d_out, B);
}

// Round 4
// 1352.286 us; speedup vs baseline: 12.2467x; 1.2069x over previous
//
#include <hip/hip_runtime.h>
#include <hip/hip_fp16.h>

#define TPB 256
#define EPT 16            // edges per thread in scatter_buckets
#define BNODES 4096       // nodes per coarse bucket (12 low bits)

// ---------------- coarse histogram of dst >> 12 ----------------
__global__ void hist_buckets(const int* __restrict__ dst, int* __restrict__ hist, int nE) {
    __shared__ int lh[256];
    lh[threadIdx.x] = 0;
    __syncthreads();
    int stride = gridDim.x * blockDim.x;
    for (int e = blockIdx.x * blockDim.x + threadIdx.x; e < nE; e += stride)
        atomicAdd(&lh[dst[e] >> 12], 1);
    __syncthreads();
    if (lh[threadIdx.x]) atomicAdd(&hist[threadIdx.x], lh[threadIdx.x]);
}

// ---------------- exclusive scan of 256 bucket counts ----------------
__global__ void scan256(const int* __restrict__ hist, int* __restrict__ bucketOff,
                        int* __restrict__ tails, int nE) {
    __shared__ int lds[256];
    int t = threadIdx.x;
    int v = hist[t];
    lds[t] = v;
    __syncthreads();
    for (int off = 1; off < 256; off <<= 1) {
        int u = (t >= off) ? lds[t - off] : 0;
        __syncthreads();
        lds[t] += u;
        __syncthreads();
    }
    int excl = lds[t] - v;
    bucketOff[t] = excl;
    tails[t] = excl;
    if (t == 255) bucketOff[256] = lds[255];   // == nE
}

// ---------------- scatter edges into coarse buckets (block-aggregated) ----------------
// payload: (dstLow12 << 20) | src   (requires n <= 2^20)
__global__ void scatter_buckets(const int* __restrict__ src, const int* __restrict__ dst,
                                int* __restrict__ tails, unsigned* __restrict__ bucketData,
                                int nE) {
    __shared__ int hist[256];
    __shared__ int cbase[256];
    int t = threadIdx.x;
    hist[t] = 0;
    __syncthreads();
    long base = (long)blockIdx.x * (TPB * EPT);
    int bk[EPT];
    int lo[EPT];
#pragma unroll
    for (int j = 0; j < EPT; ++j) {
        long e = base + t + (long)j * TPB;
        if (e < nE) {
            int d = dst[e];
            bk[j] = d >> 12;
            lo[j] = d & 4095;
            atomicAdd(&hist[bk[j]], 1);
        } else bk[j] = -1;
    }
    __syncthreads();
    int h = hist[t];
    cbase[t] = (h > 0) ? atomicAdd(&tails[t], h) : 0;
    __syncthreads();
    hist[t] = 0;   // reuse as block-local cursor
    __syncthreads();
#pragma unroll
    for (int j = 0; j < EPT; ++j) {
        long e = base + t + (long)j * TPB;
        if (bk[j] >= 0) {
            int r = atomicAdd(&hist[bk[j]], 1);
            unsigned s = (unsigned)src[e];
            bucketData[cbase[bk[j]] + r] = ((unsigned)lo[j] << 20) | s;
        }
    }
}

// ---------------- per-bucket: degrees -> dis, rowptr (scan), col (contiguous region) ----------------
__global__ void build_csr(const unsigned* __restrict__ bucketData,
                          const int* __restrict__ bucketOff,
                          int* __restrict__ rowptr, int* __restrict__ col,
                          float* __restrict__ dis, int n, int nE) {
    __shared__ int cnt[BNODES];     // 16 KB
    __shared__ int partial[TPB];
    int b = blockIdx.x;
    int t = threadIdx.x;
    for (int j = t; j < BNODES; j += TPB) cnt[j] = 0;
    __syncthreads();
    int e0 = bucketOff[b], e1 = bucketOff[b + 1];
    // count pass
    for (int k = e0 + t; k < e1; k += TPB)
        atomicAdd(&cnt[bucketData[k] >> 20], 1);
    __syncthreads();
    // dis from degree
    int base0 = b << 12;
    for (int j = t; j < BNODES; j += TPB) {
        int node = base0 + j;
        if (node < n) dis[node] = rsqrtf((float)cnt[j] + 1.0f);
    }
    // exclusive scan of cnt[0..4095]: serial-16 per thread + block scan of partials
    int tb = t * 16;
    int loc[16];
    int s = 0;
#pragma unroll
    for (int j = 0; j < 16; ++j) { loc[j] = s; s += cnt[tb + j]; }
    partial[t] = s;
    __syncthreads();
    for (int off = 1; off < TPB; off <<= 1) {
        int u = (t >= off) ? partial[t - off] : 0;
        __syncthreads();
        partial[t] += u;
        __syncthreads();
    }
    int pbase = (t > 0) ? partial[t - 1] : 0;
    __syncthreads();
    // write rowptr; convert cnt to global cursor
#pragma unroll
    for (int j = 0; j < 16; ++j) {
        int node = base0 + tb + j;
        int gbase = e0 + pbase + loc[j];
        cnt[tb + j] = gbase;
        if (node < n) rowptr[node] = gbase;
    }
    if (b == 0 && t == 0) rowptr[n] = nE;
    __syncthreads();
    // scatter pass: col writes land in [e0, e1) — contiguous, L2-resident
    for (int k = e0 + t; k < e1; k += TPB) {
        unsigned p = bucketData[k];
        int pos = atomicAdd(&cnt[p >> 20], 1);
        col[pos] = (int)(p & 0xFFFFFu);
    }
}

union H8 { uint4 u; __half2 h2[4]; };

// ---------------- layer 1 node kernel: hs = (x*W1)*dis  (fp16x8) ----------------
__global__ void node_l1(const float* __restrict__ x, const float* __restrict__ W1,
                        const float* __restrict__ dis, __half* __restrict__ hs, int n) {
    int i = blockIdx.x * blockDim.x + threadIdx.x;
    if (i >= n) return;
    float xd = x[i] * dis[i];
    float4 w0 = ((const float4*)W1)[0];
    float4 w1 = ((const float4*)W1)[1];
    H8 o;
    o.h2[0] = __floats2half2_rn(xd * w0.x, xd * w0.y);
    o.h2[1] = __floats2half2_rn(xd * w0.z, xd * w0.w);
    o.h2[2] = __floats2half2_rn(xd * w1.x, xd * w1.y);
    o.h2[3] = __floats2half2_rn(xd * w1.z, xd * w1.w);
    ((uint4*)hs)[i] = o.u;
}

// ---------------- fused pull + node transform (layers 1..3 boundaries) ----------------
// g = dis[i]*(sum hs_in[c] + hs_in[i]);  t = relu(g + b);  hs_out = (t @ W) * dis[i]
__global__ void pull_mid(const int* __restrict__ rowptr, const int* __restrict__ col,
                         const float* __restrict__ dis, const __half* __restrict__ hs_in,
                         const float* __restrict__ bias, const float* __restrict__ W,
                         __half* __restrict__ hs_out, int n) {
    int i = blockIdx.x * blockDim.x + threadIdx.x;
    if (i >= n) return;
    const uint4* hv = (const uint4*)hs_in;
    H8 p; p.u = hv[i];                       // self term
    float2 a0 = __half22float2(p.h2[0]);
    float2 a1 = __half22float2(p.h2[1]);
    float2 a2 = __half22float2(p.h2[2]);
    float2 a3 = __half22float2(p.h2[3]);
    int s = rowptr[i], e = rowptr[i + 1];
    for (int k = s; k < e; ++k) {
        H8 q; q.u = hv[col[k]];
        float2 b0 = __half22float2(q.h2[0]);
        float2 b1 = __half22float2(q.h2[1]);
        float2 b2 = __half22float2(q.h2[2]);
        float2 b3 = __half22float2(q.h2[3]);
        a0.x += b0.x; a0.y += b0.y; a1.x += b1.x; a1.y += b1.y;
        a2.x += b2.x; a2.y += b2.y; a3.x += b3.x; a3.y += b3.y;
    }
    float d = dis[i];
    float t[8] = {a0.x * d, a0.y * d, a1.x * d, a1.y * d,
                  a2.x * d, a2.y * d, a3.x * d, a3.y * d};
#pragma unroll
    for (int k = 0; k < 8; ++k) {
        float v = t[k] + bias[k];
        t[k] = v > 0.0f ? v : 0.0f;
    }
    float h[8];
#pragma unroll
    for (int j = 0; j < 8; ++j) {
        float acc = 0.0f;
#pragma unroll
        for (int k = 0; k < 8; ++k) acc += t[k] * W[k * 8 + j];
        h[j] = acc * d;
    }
    H8 o;
    o.h2[0] = __floats2half2_rn(h[0], h[1]);
    o.h2[1] = __floats2half2_rn(h[2], h[3]);
    o.h2[2] = __floats2half2_rn(h[4], h[5]);
    o.h2[3] = __floats2half2_rn(h[6], h[7]);
    ((uint4*)hs_out)[i] = o.u;
}

// ---------------- final pull: g = dis[i]*(sum + self), fp32 out ----------------
__global__ void pull_last(const int* __restrict__ rowptr, const int* __restrict__ col,
                          const float* __restrict__ dis, const __half* __restrict__ hs_in,
                          float* __restrict__ g, int n) {
    int i = blockIdx.x * blockDim.x + threadIdx.x;
    if (i >= n) return;
    const uint4* hv = (const uint4*)hs_in;
    H8 p; p.u = hv[i];
    float2 a0 = __half22float2(p.h2[0]);
    float2 a1 = __half22float2(p.h2[1]);
    float2 a2 = __half22float2(p.h2[2]);
    float2 a3 = __half22float2(p.h2[3]);
    int s = rowptr[i], e = rowptr[i + 1];
    for (int k = s; k < e; ++k) {
        H8 q; q.u = hv[col[k]];
        float2 b0 = __half22float2(q.h2[0]);
        float2 b1 = __half22float2(q.h2[1]);
        float2 b2 = __half22float2(q.h2[2]);
        float2 b3 = __half22float2(q.h2[3]);
        a0.x += b0.x; a0.y += b0.y; a1.x += b1.x; a1.y += b1.y;
        a2.x += b2.x; a2.y += b2.y; a3.x += b3.x; a3.y += b3.y;
    }
    float d = dis[i];
    float4* gp = (float4*)(g + (size_t)i * 8);
    gp[0] = make_float4(a0.x * d, a0.y * d, a1.x * d, a1.y * d);
    gp[1] = make_float4(a2.x * d, a2.y * d, a3.x * d, a3.y * d);
}

// ---------------- final gather: out[i][:] = g[idx[i]][:] + b4 ----------------
__global__ void gather_out(const float* __restrict__ g, const int* __restrict__ idx,
                           const float* __restrict__ b, float* __restrict__ out, int B) {
    int t = blockIdx.x * blockDim.x + threadIdx.x;
    if (t >= B * 8) return;
    int i = t >> 3, j = t & 7;
    out[t] = g[(size_t)idx[i] * 8 + j] + b[j];
}

extern "C" void kernel_launch(void* const* d_in, const int* in_sizes, int n_in,
                              void* d_out, int out_size, void* d_ws, size_t ws_size,
                              hipStream_t stream) {
    const float* x   = (const float*)d_in[0];
    const int*   ei  = (const int*)d_in[1];
    const int*   idx = (const int*)d_in[2];
    const float* W1  = (const float*)d_in[3];
    const float* b1  = (const float*)d_in[4];
    const float* W2  = (const float*)d_in[5];
    const float* b2  = (const float*)d_in[6];
    const float* W3  = (const float*)d_in[7];
    const float* b3  = (const float*)d_in[8];
    const float* W4  = (const float*)d_in[9];
    const float* b4  = (const float*)d_in[10];

    const int n = in_sizes[0];      // 1,000,000 nodes (requires n <= 2^20 for packing)
    const int E = in_sizes[1] / 2;  // 10,000,000 edges
    const int B = in_sizes[2];      // 64 graphs

    const int* src = ei;
    const int* dst = ei + E;

    // workspace layout (int elements; all float4/uint4 regions 16B-aligned):
    //   rowptr: n+4 | col: E | dis: n | hs_a: 4n (fp16x8) | hs_b: 4n | g: 8n | small
    //   bucketData (E unsigned) aliases hs_b+g (consumed in build_csr before writes)
    size_t o_rowptr = 0;
    size_t o_col    = o_rowptr + ((size_t)n + 4);
    size_t o_dis    = o_col    + (size_t)E;
    size_t o_hsa    = o_dis    + (size_t)n;
    size_t o_hsb    = o_hsa    + (size_t)n * 4;
    size_t o_g      = o_hsb    + (size_t)n * 4;
    size_t o_small  = o_g      + (size_t)n * 8;

    int*      rowptr     = (int*)d_ws + o_rowptr;
    int*      col        = (int*)d_ws + o_col;
    float*    dis        = (float*)d_ws + o_dis;
    __half*   hs_a       = (__half*)((int*)d_ws + o_hsa);
    __half*   hs_b       = (__half*)((int*)d_ws + o_hsb);
    float*    g          = (float*)d_ws + o_g;
    int*      hist       = (int*)d_ws + o_small;
    int*      bucketOff  = hist + 256;
    int*      tails      = bucketOff + 260;
    unsigned* bucketData = (unsigned*)hs_b;   // alias: 40 MB over hs_b(16MB)+g head

    const int NB = (n + BNODES - 1) / BNODES;   // coarse buckets (<= 256)
    const int gn = (n + TPB - 1) / TPB;
    const int gs = (int)(((long)E + TPB * EPT - 1) / (TPB * EPT));

    // ---- build CSR ----
    hipMemsetAsync(hist, 0, 256 * sizeof(int), stream);
    hist_buckets<<<1024, TPB, 0, stream>>>(dst, hist, E);
    scan256<<<1, 256, 0, stream>>>(hist, bucketOff, tails, E);
    scatter_buckets<<<gs, TPB, 0, stream>>>(src, dst, tails, bucketData, E);
    build_csr<<<NB, TPB, 0, stream>>>(bucketData, bucketOff, rowptr, col, dis, n, E);

    // ---- 4 GCN layers: fused pull + node transform ----
    node_l1<<<gn, TPB, 0, stream>>>(x, W1, dis, hs_a, n);
    pull_mid<<<gn, TPB, 0, stream>>>(rowptr, col, dis, hs_a, b1, W2, hs_b, n);
    pull_mid<<<gn, TPB, 0, stream>>>(rowptr, col, dis, hs_b, b2, W3, hs_a, n);
    pull_mid<<<gn, TPB, 0, stream>>>(rowptr, col, dis, hs_a, b3, W4, hs_b, n);
    pull_last<<<gn, TPB, 0, stream>>>(rowptr, col, dis, hs_b, g, n);

    gather_out<<<(B * 8 + TPB - 1) / TPB, TPB, 0, stream>>>(g, idx, b4, (float*)d_out, B);
}